// Round 5
// baseline (313.747 us; speedup 1.0000x reference)
//
#include <hip/hip_runtime.h>

// y[m,o] = sum_k x[m,k] * (W[o,k] + dW[o,k]) + bias[o],  W int4-dequant.
// M=8192, N=4096(OUT), K=4096(IN).
//
// Round 5: same 8-phase/1-barrier 256x256 schedule as round 4 (validated),
// but mfma_f32_32x32x16_f16 (2178 TF ubench vs 1955 for 16x16, 4x fewer
// instructions) + nontemporal Y stores (keep A/B panels in L3).
// Liveness/stage/wait schedule IDENTICAL to round 4:
//   reads:  p0: A[mt0-1]+B[nt0] | p1: B[nt1] | p2: A[mt2-3] | p3: -
//   stages: p0: A(buf^1,t+1) | p3: B(buf,t+2) | p4: A(buf^1... (mirror)
//   waits:  vmcnt(4) before BAR at p3/p7.

#define M_DIM 8192
#define N_DIM 4096
#define K_DIM 4096
#define NUMEL (N_DIM * K_DIM)

typedef _Float16 half_t;
typedef __attribute__((ext_vector_type(4))) _Float16 half4v;
typedef __attribute__((ext_vector_type(8))) _Float16 half8v;
typedef __attribute__((ext_vector_type(4))) float float4v;
typedef __attribute__((ext_vector_type(16))) float float16v;
typedef __attribute__((ext_vector_type(4))) int int4v;

#define KTILES 64
#define LDT 72

static __device__ __forceinline__ void gload16(const void* g, void* l) {
    __builtin_amdgcn_global_load_lds(
        (const __attribute__((address_space(1))) void*)g,
        (__attribute__((address_space(3))) void*)l, 16, 0, 0);
}

// ---------- Phase 1a: dequant+delta -> fp16, tile-packed + swizzled ----------
__global__ __launch_bounds__(256) void k_pack_w(
    const int* __restrict__ qp, const float* __restrict__ sc,
    const float* __restrict__ zr, const float* __restrict__ dwt,
    unsigned char* __restrict__ Wp)
{
    const long t = (long)blockIdx.x * 256 + threadIdx.x;
    const long flat = t * 8;
    const int g = (int)(flat >> 7);
    const float s = sc[g];
    const float zs = zr[g] * s;
    int4v q4 = *(const int4v*)(qp + (flat >> 1));
    float4v d0 = *(const float4v*)(dwt + flat);
    float4v d1 = *(const float4v*)(dwt + flat + 4);
    float d[8] = {d0[0], d0[1], d0[2], d0[3], d1[0], d1[1], d1[2], d1[3]};
    half8v vh;
#pragma unroll
    for (int j = 0; j < 4; ++j) {
        vh[2*j]   = (half_t)fmaf((float)(q4[j] & 15),        s, d[2*j]   - zs);
        vh[2*j+1] = (half_t)fmaf((float)((q4[j] >> 4) & 15), s, d[2*j+1] - zs);
    }
    const int n = (int)(flat >> 12);
    const int k = (int)(flat & 4095);
    const int row = n & 127;
    const int a = (row << 7) + ((k & 63) << 1);
    const int b = a ^ ((row & 7) << 4);
    *(half8v*)(Wp + (((size_t)((n >> 7) * KTILES + (k >> 6))) << 14) + b) = vh;
}

// ---------- Phase 1b: x fp32 -> fp16, tile-packed + swizzled ----------
__global__ __launch_bounds__(256) void k_pack_x(
    const float* __restrict__ X, unsigned char* __restrict__ Xp)
{
    const long flat = ((long)blockIdx.x * 256 + threadIdx.x) * 8;
    float4v x0 = *(const float4v*)(X + flat);
    float4v x1 = *(const float4v*)(X + flat + 4);
    half8v vh;
    vh[0] = (half_t)x0[0]; vh[1] = (half_t)x0[1];
    vh[2] = (half_t)x0[2]; vh[3] = (half_t)x0[3];
    vh[4] = (half_t)x1[0]; vh[5] = (half_t)x1[1];
    vh[6] = (half_t)x1[2]; vh[7] = (half_t)x1[3];
    const int m = (int)(flat >> 12);
    const int k = (int)(flat & 4095);
    const int row = m & 127;
    const int a = (row << 7) + ((k & 63) << 1);
    const int b = a ^ ((row & 7) << 4);
    *(half8v*)(Xp + (((size_t)((m >> 7) * KTILES + (k >> 6))) << 14) + b) = vh;
}

// ---------- 8-phase 256x256 GEMM, 32x32x16 MFMA, 1 barrier/phase ----------
#define BARX() do { __builtin_amdgcn_sched_barrier(0); \
                    __builtin_amdgcn_s_barrier(); \
                    __builtin_amdgcn_sched_barrier(0); } while(0)
#define WAITV(N) do { asm volatile("s_waitcnt vmcnt(" #N ")" ::: "memory"); \
                      __builtin_amdgcn_sched_barrier(0); } while(0)

// load A fragments for M-tiles MT0, MT0+1 (all 4 K-steps)
#define READ_A2(BUF, MT0) do { \
_Pragma("unroll") for (int i_ = 0; i_ < 2; ++i_) { \
    const int row_ = ((MT0) + i_) * 32 + l31; \
_Pragma("unroll") for (int ks_ = 0; ks_ < 4; ++ks_) \
        ah[i_][ks_] = *(const half8v*)(&lds[BUF][wm][row_ * 128 + ((ks_ * 32 + hk) ^ swzc)]); \
    } } while(0)

// load B fragments for N-tile NT (all 4 K-steps)
#define READ_B1(BUF, DST, NT) do { \
    const int row_ = bbase + (NT) * 32 + l31; \
_Pragma("unroll") for (int ks_ = 0; ks_ < 4; ++ks_) \
        DST[ks_] = *(const half8v*)(&lds[BUF][bhalf][row_ * 128 + ((ks_ * 32 + hk) ^ swzc)]); \
    } while(0)

// 8 MFMA: M-tiles MT0,MT0+1 x N-tile NT over 4 K-steps
#define MFMA_T(MT0, NT, BREG) do { \
    __builtin_amdgcn_s_setprio(1); \
_Pragma("unroll") for (int i_ = 0; i_ < 2; ++i_) \
_Pragma("unroll") for (int ks_ = 0; ks_ < 4; ++ks_) \
        acc[(MT0)+i_][NT] = __builtin_amdgcn_mfma_f32_32x32x16_f16( \
            ah[i_][ks_], BREG[ks_], acc[(MT0)+i_][NT], 0, 0, 0); \
    __builtin_amdgcn_s_setprio(0); \
} while(0)

__global__ __launch_bounds__(512, 2) void k_gemm8ph(
    const unsigned char* __restrict__ Apk, const unsigned char* __restrict__ Bpk,
    const float* __restrict__ bias, float* __restrict__ Y)
{
    __shared__ __align__(16) unsigned char lds[2][4][16384];  // [buf][A0,A1,B0,B1]

    const int tid  = threadIdx.x;
    const int lane = tid & 63;
    const int wave = tid >> 6;
    const int wm = wave >> 2;              // M half (128 rows)
    const int wn = wave & 3;               // N quarter (64 cols)
    const int bhalf = 2 + (wn >> 1);
    const int bbase = (wn & 1) * 64;
    const int l31  = lane & 31;
    const int hk   = (lane >> 5) << 4;     // 16B k-half select
    const int swzc = (lane & 7) << 4;      // (row&7)<<4 — row&7 == lane&7 here

    const int wg = blockIdx.x;
    const int swg = (wg & 7) * 64 + (wg >> 3);   // 512 blocks, 8 XCDs, bijective
    const int bn = swg & 15;
    const int bm = swg >> 4;

    auto asrc = [&](int h, int tk) {
        return Apk + ((((size_t)(2 * bm + h)) * KTILES + tk) << 14);
    };
    auto bsrc = [&](int h, int tk) {
        return Bpk + ((((size_t)(2 * bn + h)) * KTILES + tk) << 14);
    };
    auto stageh = [&](int b, int h, const unsigned char* s) {
        unsigned char* d = &lds[b][h][tid << 4];
        gload16(s + (tid << 4), d);
        gload16(s + 8192 + (tid << 4), d + 8192);
    };

    half8v ah[2][4], bn0[4], bn1[4];
    float16v acc[4][2];
#pragma unroll
    for (int i = 0; i < 4; ++i)
#pragma unroll
        for (int j = 0; j < 2; ++j)
#pragma unroll
            for (int e = 0; e < 16; ++e) acc[i][j][e] = 0.f;

    // ---- prologue: tile0 -> buf0 (4 halves); B(tile1) -> buf1 ----
    stageh(0, 0, asrc(0, 0)); stageh(0, 1, asrc(1, 0));
    stageh(0, 2, bsrc(0, 0)); stageh(0, 3, bsrc(1, 0));
    stageh(1, 2, bsrc(0, 1)); stageh(1, 3, bsrc(1, 1));
    WAITV(4);
    BARX();

    for (int it = 0; it < 31; ++it) {
        const int t1 = 2 * it + 1, t2 = 2 * it + 2, t3 = 2 * it + 3;
        // p0: read buf0 A[mt0-1],B[nt0]; stage A(buf1,t1)
        READ_A2(0, 0); READ_B1(0, bn0, 0);
        stageh(1, 0, asrc(0, t1)); stageh(1, 1, asrc(1, t1));
        BARX();
        MFMA_T(0, 0, bn0);
        // p1: read B[nt1](buf0)
        READ_B1(0, bn1, 1);
        BARX();
        MFMA_T(0, 1, bn1);
        // p2: read A[mt2-3](buf0)
        READ_A2(0, 2);
        BARX();
        MFMA_T(2, 1, bn1);
        // p3: stage B(buf0,t2); drain for buf1 t1
        stageh(0, 2, bsrc(0, t2)); stageh(0, 3, bsrc(1, t2));
        WAITV(4);
        BARX();
        MFMA_T(2, 0, bn0);
        // p4: read buf1 A[mt0-1],B[nt0]; stage A(buf0,t2)
        READ_A2(1, 0); READ_B1(1, bn0, 0);
        stageh(0, 0, asrc(0, t2)); stageh(0, 1, asrc(1, t2));
        BARX();
        MFMA_T(0, 0, bn0);
        // p5
        READ_B1(1, bn1, 1);
        BARX();
        MFMA_T(0, 1, bn1);
        // p6
        READ_A2(1, 2);
        BARX();
        MFMA_T(2, 1, bn1);
        // p7: stage B(buf1,t3); drain for buf0 t2
        stageh(1, 2, bsrc(0, t3)); stageh(1, 3, bsrc(1, t3));
        WAITV(4);
        BARX();
        MFMA_T(2, 0, bn0);
    }

    // ---- tail: K-tiles 62 (buf0), 63 (buf1) ----
    READ_A2(0, 0); READ_B1(0, bn0, 0);
    stageh(1, 0, asrc(0, 63)); stageh(1, 1, asrc(1, 63));
    BARX(); MFMA_T(0, 0, bn0);
    READ_B1(0, bn1, 1);
    BARX(); MFMA_T(0, 1, bn1);
    READ_A2(0, 2);
    BARX(); MFMA_T(2, 1, bn1);
    WAITV(0);
    BARX(); MFMA_T(2, 0, bn0);
    READ_A2(1, 0); READ_B1(1, bn0, 0);
    BARX(); MFMA_T(0, 0, bn0);
    READ_B1(1, bn1, 1);
    BARX(); MFMA_T(0, 1, bn1);
    READ_A2(1, 2);
    BARX(); MFMA_T(2, 1, bn1);
    MFMA_T(2, 0, bn0);

    // ---- epilogue: 32x32 C/D map col=lane&31, row=(reg&3)+8*(reg>>2)+4*(lane>>5)
    const long m0 = (long)bm * 256 + wm * 128;
    const long n0 = (long)bn * 256 + wn * 64;
    const int rbase = (lane >> 5) * 4;
#pragma unroll
    for (int mt = 0; mt < 4; ++mt) {
#pragma unroll
        for (int nt = 0; nt < 2; ++nt) {
            const long col = n0 + nt * 32 + l31;
            const float b = bias[col];
#pragma unroll
            for (int q = 0; q < 4; ++q) {
                const long row = m0 + mt * 32 + 8 * q + rbase;
#pragma unroll
                for (int r = 0; r < 4; ++r)
                    __builtin_nontemporal_store(acc[mt][nt][q * 4 + r] + b,
                                                &Y[(row + r) * N_DIM + col]);
            }
        }
    }
}

// ---------- fallback (no workspace): fused dequant 128x128 GEMM ----------
__global__ __launch_bounds__(256, 2) void k_gemm_fused(
    const float* __restrict__ X, const int* __restrict__ qp,
    const float* __restrict__ sc, const float* __restrict__ zr,
    const float* __restrict__ dwt,
    const float* __restrict__ bias, float* __restrict__ Y)
{
    __shared__ __align__(16) half_t Ah[128 * LDT];
    __shared__ __align__(16) half_t Bh[128 * LDT];

    const int tid  = threadIdx.x;
    const int lane = tid & 63;
    const int wave = tid >> 6;
    const int wm = wave >> 1, wn = wave & 1;
    const int bn = blockIdx.x & 31;
    const int bm = blockIdx.x >> 5;
    const long m0 = (long)bm * 128;
    const long n0 = (long)bn * 128;
    const int fr = lane & 15;
    const int ko = (lane >> 4) * 8;

    const float4v zero4 = {0.f, 0.f, 0.f, 0.f};
    float4v acc[4][4];
#pragma unroll
    for (int i = 0; i < 4; ++i)
#pragma unroll
        for (int j = 0; j < 4; ++j) acc[i][j] = zero4;

    for (int k0 = 0; k0 < K_DIM; k0 += 64) {
        {
            const int ar = tid >> 4;
            const int ac = (tid & 15) * 4;
#pragma unroll
            for (int rr = 0; rr < 8; ++rr) {
                const int row = ar + rr * 16;
                float4v xv = *(const float4v*)(X + (m0 + row) * K_DIM + k0 + ac);
                half4v h;
#pragma unroll
                for (int j = 0; j < 4; ++j) h[j] = (half_t)xv[j];
                *(half4v*)(Ah + row * LDT + ac) = h;
            }
        }
        {
            const int cr = tid >> 3;
            const int cc = (tid & 7) * 8;
#pragma unroll
            for (int rr = 0; rr < 4; ++rr) {
                const int row = cr + rr * 32;
                const long n = n0 + row;
                const int g = (int)(n * 32 + (k0 >> 7));
                const float s = sc[g];
                const float zs = zr[g] * s;
                const long flat = n * K_DIM + k0 + cc;
                int4v q4 = *(const int4v*)(qp + (flat >> 1));
                float4v d0 = *(const float4v*)(dwt + flat);
                float4v d1 = *(const float4v*)(dwt + flat + 4);
                float d[8] = {d0[0], d0[1], d0[2], d0[3], d1[0], d1[1], d1[2], d1[3]};
                half8v vh;
#pragma unroll
                for (int j = 0; j < 4; ++j) {
                    vh[2*j]   = (half_t)fmaf((float)(q4[j] & 15),        s, d[2*j]   - zs);
                    vh[2*j+1] = (half_t)fmaf((float)((q4[j] >> 4) & 15), s, d[2*j+1] - zs);
                }
                *(half8v*)(Bh + row * LDT + cc) = vh;
            }
        }
        __syncthreads();
#pragma unroll
        for (int ks = 0; ks < 2; ++ks) {
            const int kk = ks * 32 + ko;
            half8v a2[4], b2[4];
#pragma unroll
            for (int i = 0; i < 4; ++i) {
                a2[i] = *(const half8v*)(Ah + (wm * 64 + i * 16 + fr) * LDT + kk);
                b2[i] = *(const half8v*)(Bh + (wn * 64 + i * 16 + fr) * LDT + kk);
            }
#pragma unroll
            for (int i = 0; i < 4; ++i)
#pragma unroll
                for (int j = 0; j < 4; ++j)
                    acc[i][j] = __builtin_amdgcn_mfma_f32_16x16x32_f16(
                        a2[i], b2[j], acc[i][j], 0, 0, 0);
        }
        __syncthreads();
    }

#pragma unroll
    for (int i = 0; i < 4; ++i) {
        const long mrow = m0 + wm * 64 + i * 16 + (lane >> 4) * 4;
#pragma unroll
        for (int j = 0; j < 4; ++j) {
            const long col = n0 + wn * 64 + j * 16 + (lane & 15);
            const float b = bias[col];
#pragma unroll
            for (int r = 0; r < 4; ++r)
                Y[(mrow + r) * N_DIM + col] = acc[i][j][r] + b;
        }
    }
}

extern "C" void kernel_launch(void* const* d_in, const int* in_sizes, int n_in,
                              void* d_out, int out_size, void* d_ws, size_t ws_size,
                              hipStream_t stream)
{
    const float* X  = (const float*)d_in[0];
    const int*   qp = (const int*)d_in[1];
    const float* sc = (const float*)d_in[2];
    const float* zr = (const float*)d_in[3];
    const float* dwt = (const float*)d_in[4];
    const float* bs = (const float*)d_in[5];
    float* Y = (float*)d_out;

    const size_t needB = (size_t)N_DIM * K_DIM * 2;
    const size_t needA = (size_t)M_DIM * K_DIM * 2;

    if (ws_size >= needA + needB) {
        unsigned char* Bpk = (unsigned char*)d_ws;
        unsigned char* Apk = Bpk + needB;
        k_pack_w<<<dim3(NUMEL / 8 / 256), dim3(256), 0, stream>>>(qp, sc, zr, dwt, Bpk);
        k_pack_x<<<dim3((M_DIM * (size_t)K_DIM) / 8 / 256), dim3(256), 0, stream>>>(X, Apk);
        k_gemm8ph<<<dim3((M_DIM / 256) * (N_DIM / 256)), dim3(512), 0, stream>>>(Apk, Bpk, bs, Y);
    } else {
        k_gemm_fused<<<dim3((M_DIM / 128) * (N_DIM / 128)), dim3(256), 0, stream>>>(
            X, qp, sc, zr, dwt, bs, Y);
    }
}